// Round 6
// baseline (235.797 us; speedup 1.0000x reference)
//
#include <hip/hip_runtime.h>

#define B_DIM 8
#define T_DIM 2048
#define C_DIM 1024
#define H_DIM 128

typedef __attribute__((ext_vector_type(8))) short bf16x8;
typedef __attribute__((ext_vector_type(4))) float f32x4;

__device__ __forceinline__ short f2bf(float f) {
  union { float f; unsigned u; } v; v.f = f;
  unsigned u = v.u;
  unsigned r = (u + 0x7FFFu + ((u >> 16) & 1u)) >> 16;
  return (short)r;
}

__device__ __forceinline__ float bf2f(short s) {
  union { float f; unsigned u; } v;
  v.u = ((unsigned)(unsigned short)s) << 16;
  return v.f;
}

// pack two fp32 -> two bf16 (round-half-up). 3 VALU.
__device__ __forceinline__ unsigned pk2(float a, float b) {
  union { float f; unsigned u; } ua, ub;
  ua.f = a; ub.f = b;
  return __builtin_amdgcn_perm(ub.u + 0x8000u, ua.u + 0x8000u, 0x07060302u);
}

// segments-before-tile prefix for BM=128, seg<=4 iters: nseg(qt) = (qt>>1)+1
__device__ __forceinline__ int segP(int q) {  // segs in tiles < q
  int a = q >> 1;
  return (q & 1) ? (a + 1) * (a + 1) : a * (a + 1);
}

// ---------------------------------------------------------------------------
// prep: W{k,q,v} [C][H] fp32 -> Wt[384][1024] bf16 transposed (row=h', col=c)
// ---------------------------------------------------------------------------
__global__ __launch_bounds__(256) void prep_kernel(
    const float* __restrict__ Wk, const float* __restrict__ Wq,
    const float* __restrict__ Wv, short* __restrict__ Wt) {
  int idx = blockIdx.x * 256 + threadIdx.x;   // 0 .. 393215
  int c = idx & 1023;
  int hw = idx >> 10;
  int h = hw & 127;
  int w = hw >> 7;
  const float* W = (w == 0) ? Wk : ((w == 1) ? Wq : Wv);
  Wt[((w * 128 + h) << 10) + c] = f2bf(W[(c << 7) + h]);
}

// ---------------------------------------------------------------------------
// proj: out[m][h'] = sum_c x[m][c]*Wt[h'][c].  64x128 tile, BK=32, 768 blocks.
// 4 waves 2x2 (wave tile 32x64).  g: 0->Kb, 1->Qb row-major; 2->Vt [b][h][t].
// ---------------------------------------------------------------------------
__global__ __launch_bounds__(256) void proj_kernel(
    const float* __restrict__ x, const short* __restrict__ Wt,
    short* __restrict__ Kb, short* __restrict__ Qb, short* __restrict__ Vt) {
  __shared__ __align__(16) char smem[18432];
  short* As = (short*)smem;                 // [64][32]  4 KB
  short* Bs = (short*)(smem + 4096);        // [128][32] 8 KB
  short (*Tp1)[136] = (short(*)[136])smem;  // [64][136] repack (g<2)
  short (*Tp2)[72]  = (short(*)[72])smem;   // [128][72] repack (g=2)

  const int g  = blockIdx.y;
  const int m0 = blockIdx.x * 64;
  const int tid  = threadIdx.x;
  const int lane = tid & 63;
  const int wv   = tid >> 6;
  const int n    = lane & 15;
  const int quad = lane >> 4;
  const int mbase = (wv >> 1) * 32;
  const int nbase = (wv & 1) * 64;

  // A stage: row = tid>>2 (0..63), 8 k-elems; B stage: row = tid>>1, 16 elems
  const int arow  = tid >> 2;
  const int acol8 = (tid & 3) * 8;
  const int brow  = tid >> 1;
  const int bc16  = (tid & 1) * 16;
  const float* gA = x + (size_t)(m0 + arow) * C_DIM + acol8;
  const short* gB = Wt + (size_t)(g * 128 + brow) * C_DIM + bc16;

  float4 fA[2];
  int4 rB[2];
#pragma unroll
  for (int j = 0; j < 2; j++) fA[j] = ((const float4*)gA)[j];
#pragma unroll
  for (int j = 0; j < 2; j++) rB[j] = ((const int4*)gB)[j];

  f32x4 acc[2][4];
#pragma unroll
  for (int i = 0; i < 2; i++)
#pragma unroll
    for (int j = 0; j < 4; j++) {
      f32x4 z = {0.f, 0.f, 0.f, 0.f};
      acc[i][j] = z;
    }

  for (int k0 = 0; k0 < C_DIM; k0 += 32) {
    __syncthreads();
    {
      __attribute__((aligned(16))) unsigned ua[4];
      ua[0] = pk2(fA[0].x, fA[0].y); ua[1] = pk2(fA[0].z, fA[0].w);
      ua[2] = pk2(fA[1].x, fA[1].y); ua[3] = pk2(fA[1].z, fA[1].w);
      *(int4*)(As + arow * 32 + acol8) = *(int4*)ua;
      ((int4*)(Bs + brow * 32 + bc16))[0] = rB[0];
      ((int4*)(Bs + brow * 32 + bc16))[1] = rB[1];
    }
    __syncthreads();
    if (k0 + 32 < C_DIM) {
#pragma unroll
      for (int j = 0; j < 2; j++) fA[j] = ((const float4*)(gA + k0 + 32))[j];
#pragma unroll
      for (int j = 0; j < 2; j++) rB[j] = ((const int4*)(gB + k0 + 32))[j];
    }

    bf16x8 aF[2], bF[4];
#pragma unroll
    for (int mt = 0; mt < 2; mt++)
      aF[mt] = *(const bf16x8*)(As + (mbase + mt * 16 + n) * 32 + quad * 8);
#pragma unroll
    for (int nt = 0; nt < 4; nt++)
      bF[nt] = *(const bf16x8*)(Bs + (nbase + nt * 16 + n) * 32 + quad * 8);
#pragma unroll
    for (int mt = 0; mt < 2; mt++)
#pragma unroll
      for (int nt = 0; nt < 4; nt++)
        acc[mt][nt] = __builtin_amdgcn_mfma_f32_16x16x32_bf16(
            aF[mt], bF[nt], acc[mt][nt], 0, 0, 0);
  }

  // epilogue: repack through LDS for coalesced stores
  __syncthreads();
#pragma unroll
  for (int mt = 0; mt < 2; mt++)
#pragma unroll
    for (int nt = 0; nt < 4; nt++)
#pragma unroll
      for (int i = 0; i < 4; i++) {
        int rowt = mbase + mt * 16 + quad * 4 + i;  // 0..63 (t-local)
        int colh = nbase + nt * 16 + n;             // 0..127 (h)
        short v = f2bf(acc[mt][nt][i]);
        if (g == 2) Tp2[colh][rowt] = v;
        else        Tp1[rowt][colh] = v;
      }
  __syncthreads();
  if (g == 2) {
    int hrow = tid >> 1, th = (tid & 1) * 32;      // 32 t-elems
    int bb = m0 >> 11, t0 = m0 & (T_DIM - 1);
    short* dst = Vt + ((size_t)bb * H_DIM + hrow) * T_DIM + t0 + th;
    const short* src = &Tp2[hrow][th];
#pragma unroll
    for (int j = 0; j < 4; j++)
      *(int4*)(dst + j * 8) = *(const int4*)(src + j * 8);
  } else {
    int row = tid >> 2, qtr = (tid & 3) * 32;      // 32 h-elems
    short* base = (g == 0) ? Kb : Qb;
    short* dst = base + (size_t)(m0 + row) * H_DIM + qtr;
    const short* src = &Tp1[row][qtr];
#pragma unroll
    for (int j = 0; j < 4; j++)
      *(int4*)(dst + j * 8) = *(const int4*)(src + j * 8);
  }
}

// ---------------------------------------------------------------------------
// attn pass 1: BM=128 (8 waves), BN=64, segments of <=4 KV-iters.
// 72 segments per b (heavy-first).  S^T via MFMA operand swap.
// Partials: Opart bf16 [pid][128 q][128 h], Ml fp32 [pid][m 128 | l 128].
// ---------------------------------------------------------------------------
__global__ __launch_bounds__(512) void attn_part(
    const short* __restrict__ Qb, const short* __restrict__ Kb,
    const short* __restrict__ Vt, short* __restrict__ Opart,
    float* __restrict__ Ml) {
  const int f = 71 - blockIdx.x;   // heavy (qt=15) first
  const int b = blockIdx.y;
  int qt = 0;
  while (qt < 15 && segP(qt + 1) <= f) qt++;
  const int seg  = f - segP(qt);
  const int nseg = (qt >> 1) + 1;
  const int n_it = 2 * qt + 2;
  const int bi = n_it / nseg, rem = n_it - bi * nseg;
  const int it0 = seg * bi + (seg < rem ? seg : rem);
  const int it1 = it0 + bi + (seg < rem ? 1 : 0);

  const int tid  = threadIdx.x;
  const int lane = tid & 63;
  const int wv   = tid >> 6;       // 0..7
  const int n    = lane & 15;
  const int quad = lane >> 4;

  __shared__ short Ks[64][136];    // 17.4 KB
  __shared__ short Vs[128][72];    // 18.4 KB
  __shared__ short Ps[8][16][72];  // 18.4 KB  (54.2 KB total -> 2 blocks/CU)

  const int qbase = qt * 128 + wv * 16;     // wave's first q row
  const int qg = qbase + n;                 // this lane's q (S^T col)

  bf16x8 aQ[4];
  {
    const short* qrow = Qb + (size_t)(b * T_DIM + qbase + n) * H_DIM;
#pragma unroll
    for (int kc = 0; kc < 4; kc++)
      aQ[kc] = *(const bf16x8*)(qrow + kc * 32 + quad * 8);
  }

  f32x4 accO[8];
#pragma unroll
  for (int i = 0; i < 8; i++) {
    f32x4 z = {0.f, 0.f, 0.f, 0.f};
    accO[i] = z;
  }
  float mrow = -1e30f, lrow = 0.f;
  const float scale = 0.08838834764831845f;  // 1/sqrt(128)

  const short* kbase = Kb + (size_t)b * T_DIM * H_DIM;
  const short* vbase = Vt + (size_t)b * H_DIM * T_DIM;
  // staging: 1024 16B-chunks per tile, 2 per thread
  const int krow = tid >> 4, kcol = (tid & 15) * 8;   // rows 0..31 (+32)
  const int vrow = tid >> 3, vcol = (tid & 7) * 8;    // rows 0..63 (+64)

  int4 kreg[2], vreg[2];
#pragma unroll
  for (int p = 0; p < 2; p++) {
    kreg[p] = *(const int4*)(kbase + (size_t)(it0 * 64 + krow + p * 32) * H_DIM + kcol);
    vreg[p] = *(const int4*)(vbase + (size_t)(vrow + p * 64) * T_DIM + it0 * 64 + vcol);
  }

  for (int it = it0; it < it1; ++it) {
    const int j0 = it * 64;
    __syncthreads();
#pragma unroll
    for (int p = 0; p < 2; p++) *(int4*)&Ks[krow + p * 32][kcol] = kreg[p];
#pragma unroll
    for (int p = 0; p < 2; p++) *(int4*)&Vs[vrow + p * 64][vcol] = vreg[p];
    __syncthreads();
    if (it + 1 < it1) {
#pragma unroll
      for (int p = 0; p < 2; p++) {
        kreg[p] = *(const int4*)(kbase + (size_t)(j0 + 64 + krow + p * 32) * H_DIM + kcol);
        vreg[p] = *(const int4*)(vbase + (size_t)(vrow + p * 64) * T_DIM + j0 + 64 + vcol);
      }
    }

    // wave-level skip: this iter entirely above the causal diagonal for wave
    if (j0 > qbase + 15) continue;

    // St = K·Q^T : C col = q-local n, row = mt*16+quad*4+i = kv-local
    f32x4 accS[4];
#pragma unroll
    for (int mt = 0; mt < 4; mt++) {
      f32x4 z = {0.f, 0.f, 0.f, 0.f};
      accS[mt] = z;
    }
#pragma unroll
    for (int mt = 0; mt < 4; mt++)
#pragma unroll
      for (int kc = 0; kc < 4; kc++) {
        bf16x8 aK = *(const bf16x8*)&Ks[mt * 16 + n][kc * 32 + quad * 8];
        accS[mt] = __builtin_amdgcn_mfma_f32_16x16x32_bf16(aK, aQ[kc], accS[mt], 0, 0, 0);
      }

    float sv[4][4];
    float mx = -1e30f;
#pragma unroll
    for (int mt = 0; mt < 4; mt++) {
      int kvb = j0 + mt * 16 + quad * 4;
#pragma unroll
      for (int i = 0; i < 4; i++) {
        float s = accS[mt][i] * scale;
        if (kvb + i > qg) s = -1e30f;
        sv[mt][i] = s;
        mx = fmaxf(mx, s);
      }
    }
    mx = fmaxf(mx, __shfl_xor(mx, 16, 64));
    mx = fmaxf(mx, __shfl_xor(mx, 32, 64));
    float mnew = fmaxf(mrow, mx);
    float alpha = __expf(mrow - mnew);
    mrow = mnew;
    float rsum = 0.f;
#pragma unroll
    for (int mt = 0; mt < 4; mt++)
#pragma unroll
      for (int i = 0; i < 4; i++) {
        // masked lanes: exp(-1e30 - (-1e30)) = 1 trap -> explicit zero
        float p = (sv[mt][i] > -5e29f) ? __expf(sv[mt][i] - mnew) : 0.f;
        rsum += p;
        Ps[wv][n][mt * 16 + quad * 4 + i] = f2bf(p);
      }
    rsum += __shfl_xor(rsum, 16, 64);
    rsum += __shfl_xor(rsum, 32, 64);
    lrow = lrow * alpha + rsum;

    float aR[4];
#pragma unroll
    for (int i = 0; i < 4; i++) aR[i] = __shfl(alpha, quad * 4 + i, 64);
#pragma unroll
    for (int ht = 0; ht < 8; ht++)
#pragma unroll
      for (int i = 0; i < 4; i++)
        accO[ht][i] *= aR[i];

    // O += P·V (Ps per-wave; in-wave DS ordering suffices — verified R5)
    bf16x8 aP[2];
#pragma unroll
    for (int kc = 0; kc < 2; kc++)
      aP[kc] = *(const bf16x8*)&Ps[wv][n][kc * 32 + quad * 8];
#pragma unroll
    for (int ht = 0; ht < 8; ht++)
#pragma unroll
      for (int kc = 0; kc < 2; kc++) {
        bf16x8 bV = *(const bf16x8*)&Vs[ht * 16 + n][kc * 32 + quad * 8];
        accO[ht] = __builtin_amdgcn_mfma_f32_16x16x32_bf16(aP[kc], bV, accO[ht], 0, 0, 0);
      }
  }

  // partials: Opart bf16, rows q-local (wv*16+quad*4+i), cols h (ht*16+n)
  const int pid = b * 72 + f;
  short* Ob = Opart + (size_t)pid * 16384;
#pragma unroll
  for (int ht = 0; ht < 8; ht++)
#pragma unroll
    for (int i = 0; i < 4; i++)
      Ob[(wv * 16 + quad * 4 + i) * 128 + ht * 16 + n] = f2bf(accO[ht][i]);
  if (quad == 0) {
    Ml[pid * 256 + wv * 16 + n] = mrow;
    Ml[pid * 256 + 128 + wv * 16 + n] = lrow;
  }
}

// ---------------------------------------------------------------------------
// attn pass 2: merge <=8 bf16 partials per (b, qt tile of 128), write fp32.
// ---------------------------------------------------------------------------
__global__ __launch_bounds__(256) void attn_merge(
    const short* __restrict__ Opart, const float* __restrict__ Ml,
    float* __restrict__ out) {
  const int qt = blockIdx.x, b = blockIdx.y;   // qt 0..15
  const int nseg = (qt >> 1) + 1;
  const int tid = threadIdx.x;
  const int row = tid >> 1;            // q-local 0..127
  const int half = (tid & 1) * 64;     // h offset
  const int pid0 = b * 72 + segP(qt);

  float m[8], l[8], w[8];
  float M = -1e30f;
  for (int s = 0; s < nseg; s++) {
    m[s] = Ml[(pid0 + s) * 256 + row];
    l[s] = Ml[(pid0 + s) * 256 + 128 + row];
    M = fmaxf(M, m[s]);
  }
  float L = 0.f;
  for (int s = 0; s < nseg; s++) {
    w[s] = __expf(m[s] - M);
    L += l[s] * w[s];
  }
  const float inv = 1.0f / L;

  float accv[64];
#pragma unroll
  for (int c = 0; c < 64; c++) accv[c] = 0.f;
  for (int s = 0; s < nseg; s++) {
    const short* src = Opart + (size_t)(pid0 + s) * 16384 + row * 128 + half;
#pragma unroll
    for (int j = 0; j < 8; j++) {
      bf16x8 v = ((const bf16x8*)src)[j];
#pragma unroll
      for (int e = 0; e < 8; e++) accv[j * 8 + e] += w[s] * bf2f(v[e]);
    }
  }
  float* dst = out + (size_t)(b * T_DIM + qt * 128 + row) * H_DIM + half;
#pragma unroll
  for (int c = 0; c < 64; c++) dst[c] = accv[c] * inv;
}

// ---------------------------------------------------------------------------
extern "C" void kernel_launch(void* const* d_in, const int* in_sizes, int n_in,
                              void* d_out, int out_size, void* d_ws, size_t ws_size,
                              hipStream_t stream) {
  (void)in_sizes; (void)n_in; (void)out_size; (void)ws_size;
  const float* x  = (const float*)d_in[0];
  const float* Wk = (const float*)d_in[1];
  const float* Wq = (const float*)d_in[2];
  const float* Wv = (const float*)d_in[3];
  float* out = (float*)d_out;

  char* ws = (char*)d_ws;
  short* Wt = (short*)ws;                       //    786,432 B
  short* Qb = (short*)(ws + 786432);            //  4,194,304 B
  short* Kb = (short*)(ws + 4980736);           //  4,194,304 B
  short* Vt = (short*)(ws + 9175040);           //  4,194,304 B
  short* Opart = (short*)(ws + 13369344);       // 18,874,368 B (576 x 32 KB, bf16)
  float* Ml    = (float*)(ws + 32243712);       //    589,824 B  (peak 31.3 MiB)

  prep_kernel<<<dim3(1536), dim3(256), 0, stream>>>(Wk, Wq, Wv, Wt);
  proj_kernel<<<dim3(256, 3), dim3(256), 0, stream>>>(x, Wt, Kb, Qb, Vt);
  attn_part<<<dim3(72, 8), dim3(512), 0, stream>>>(Qb, Kb, Vt, Opart, Ml);
  attn_merge<<<dim3(16, 8), dim3(256), 0, stream>>>(Opart, Ml, out);
}